// Round 3
// baseline (4864.947 us; speedup 1.0000x reference)
//
#include <hip/hip_runtime.h>
#include <stdint.h>

#define T_ 512
#define B_ 64
#define E_ 256
#define H_ 512
#define KT 50

typedef __attribute__((ext_vector_type(8))) short bf16x8;
typedef __attribute__((ext_vector_type(4))) float f32x4;
typedef __attribute__((ext_vector_type(4))) int i32x4;

#define MFMA16(a,b,c) __builtin_amdgcn_mfma_f32_16x16x32_bf16((a),(b),(c),0,0,0)

static __device__ __forceinline__ float bf2f(unsigned short v) {
  unsigned int u = ((unsigned int)v) << 16; float f; __builtin_memcpy(&f, &u, 4); return f;
}
static __device__ __forceinline__ unsigned short f2bf(float f) {
  unsigned int u; __builtin_memcpy(&u, &f, 4);
  u += 0x7fffu + ((u >> 16) & 1u);
  return (unsigned short)(u >> 16);
}
static __device__ __forceinline__ float sigm(float x) { return 1.f / (1.f + __expf(-x)); }
static __device__ __forceinline__ float tanh_(float x) { return 2.f / (1.f + __expf(-2.f * x)) - 1.f; }

// device-scope (MALL) dword load, self-waiting — for single-word tag polls
static __device__ __forceinline__ unsigned int load_dw_dev(const unsigned int* p) {
  unsigned int v;
  asm volatile("global_load_dword %0, %1, off sc0 sc1\n\ts_waitcnt vmcnt(0)"
               : "=v"(v) : "v"(p) : "memory");
  return v;
}

// ------------------------------------------------------------- dtype probe
__global__ void probe_kernel(const unsigned short* __restrict__ e,
                             unsigned int* __restrict__ flag) {
  int lane = threadIdx.x & 63;
  float a = fabsf(bf2f(e[2 * lane]));
  int good = (a >= 1e-8f && a <= 4.0f);
  unsigned long long m = __ballot(good);
  if (threadIdx.x == 0) flag[0] = (__popcll(m) >= 48) ? 1u : 0u;
}

// ------------------------------------------------------------- canonicalize
struct CvtArgs { const void* src; unsigned short* dst; int n; };
struct CvtPack { CvtArgs a[11]; };

__global__ __launch_bounds__(256) void convert_kernel(CvtPack p,
                                                      const unsigned int* __restrict__ flag) {
  CvtArgs c = p.a[blockIdx.y];
  int i = (blockIdx.x * 256 + threadIdx.x) * 8;
  if (i >= c.n) return;
  int isbf = *flag;
  if (i + 8 <= c.n) {
    if (isbf) {
      *(i32x4*)(c.dst + i) = *(const i32x4*)((const unsigned short*)c.src + i);
    } else {
      const float* s = (const float*)c.src;
      float4 a0 = *(const float4*)(s + i);
      float4 a1 = *(const float4*)(s + i + 4);
      unsigned short o[8] = {f2bf(a0.x), f2bf(a0.y), f2bf(a0.z), f2bf(a0.w),
                             f2bf(a1.x), f2bf(a1.y), f2bf(a1.z), f2bf(a1.w)};
      *(i32x4*)(c.dst + i) = *(i32x4*)o;
    }
  } else {
    for (int j = 0; j < 8; j++) {
      if (i + j < c.n) {
        c.dst[i + j] = isbf ? ((const unsigned short*)c.src)[i + j]
                            : f2bf(((const float*)c.src)[i + j]);
      }
    }
  }
}

// ---------------------------------------------------------------- embedding
__global__ __launch_bounds__(256) void embed_kernel(
    const int* __restrict__ tokens, const void* __restrict__ embed,
    const unsigned int* __restrict__ flag, unsigned short* __restrict__ x) {
  int tid = threadIdx.x;
  int row = blockIdx.x * 8 + (tid >> 5);   // row = t*64+b, 32768 rows
  int l = tid & 31;
  int tok = tokens[row];
  if (*flag) {
    const unsigned short* e = (const unsigned short*)embed;
    *(i32x4*)(x + (size_t)row * E_ + l * 8) =
        *(const i32x4*)(e + (size_t)tok * E_ + l * 8);
  } else {
    const float* e = (const float*)embed + (size_t)tok * E_ + l * 8;
    float4 a0 = *(const float4*)e;
    float4 a1 = *(const float4*)(e + 4);
    unsigned short o[8] = {f2bf(a0.x), f2bf(a0.y), f2bf(a0.z), f2bf(a0.w),
                           f2bf(a1.x), f2bf(a1.y), f2bf(a1.z), f2bf(a1.w)};
    *(i32x4*)(x + (size_t)row * E_ + l * 8) = *(i32x4*)o;
  }
}

// ---------------------------------------------------------------- poison
// Pre-poison hf|hb (contiguous 64 MB) with 0xFFFFFFFF via device-scope
// stores. 0xFFFF bf16 = NaN, unreachable for sigm*tanh outputs (|h| < 1),
// so any poisoned dword means "not yet published".
__global__ __launch_bounds__(256) void poison_kernel(unsigned int* __restrict__ p) {
  i32x4 v; v[0] = -1; v[1] = -1; v[2] = -1; v[3] = -1;
  unsigned int* a = p + (size_t)blockIdx.x * 8192 + (size_t)threadIdx.x * 4;
#pragma unroll
  for (int k = 0; k < 8; k++) {
    asm volatile("global_store_dwordx4 %0, %1, off sc0 sc1" :: "v"(a), "v"(v) : "memory");
    a += 1024;
  }
}

// x-staging: 8 dwordx4 loads for one timestep, issued a step early.
#define ISSUE_BX(tt)                                                          \
  do {                                                                        \
    const unsigned short* xb_ = x + (size_t)(tt) * (B_ * E_);                 \
    const unsigned short* x0_ = xb_ + (size_t)(0 * 16 + l15) * E_ + (wv * 2 + 0) * 32 + q * 8; \
    const unsigned short* x1_ = xb_ + (size_t)(1 * 16 + l15) * E_ + (wv * 2 + 0) * 32 + q * 8; \
    const unsigned short* x2_ = xb_ + (size_t)(2 * 16 + l15) * E_ + (wv * 2 + 0) * 32 + q * 8; \
    const unsigned short* x3_ = xb_ + (size_t)(3 * 16 + l15) * E_ + (wv * 2 + 0) * 32 + q * 8; \
    const unsigned short* x4_ = xb_ + (size_t)(0 * 16 + l15) * E_ + (wv * 2 + 1) * 32 + q * 8; \
    const unsigned short* x5_ = xb_ + (size_t)(1 * 16 + l15) * E_ + (wv * 2 + 1) * 32 + q * 8; \
    const unsigned short* x6_ = xb_ + (size_t)(2 * 16 + l15) * E_ + (wv * 2 + 1) * 32 + q * 8; \
    const unsigned short* x7_ = xb_ + (size_t)(3 * 16 + l15) * E_ + (wv * 2 + 1) * 32 + q * 8; \
    asm volatile(                                                             \
        "global_load_dwordx4 %0, %8, off\n\t"                                 \
        "global_load_dwordx4 %1, %9, off\n\t"                                 \
        "global_load_dwordx4 %2, %10, off\n\t"                                \
        "global_load_dwordx4 %3, %11, off\n\t"                                \
        "global_load_dwordx4 %4, %12, off\n\t"                                \
        "global_load_dwordx4 %5, %13, off\n\t"                                \
        "global_load_dwordx4 %6, %14, off\n\t"                                \
        "global_load_dwordx4 %7, %15, off"                                    \
        : "=&v"(bxw[0]), "=&v"(bxw[1]), "=&v"(bxw[2]), "=&v"(bxw[3]),         \
          "=&v"(bxw[4]), "=&v"(bxw[5]), "=&v"(bxw[6]), "=&v"(bxw[7])          \
        : "v"(x0_), "v"(x1_), "v"(x2_), "v"(x3_),                             \
          "v"(x4_), "v"(x5_), "v"(x6_), "v"(x7_)                              \
        : "memory");                                                          \
  } while (0)

// ---------------------------------------------------------------- BiLSTM
// 64 blocks: dir = bid&1, wg = bid>>1. Weights pinned in VGPRs. Publish and
// gather ADDRESSES byte-identical to the harness-verified round-0 kernel.
//
// HYBRID transport (tag gate + poison validate):
//  - producer: 2 dwordx4 data stores + 1 tag store, ALL fire-and-forget
//    (no vmcnt drain — removes 1 MALL RT from the producer path). Tag may
//    race data; poison validation covers the race.
//  - consumer: speculative 16-load gather at loop top (hot region read ONCE
//    — avoids round-2's data-polling read-storm that delayed the producer
//    stores), x-MFMAs under counted vmcnt(16), then the cheap tag gate
//    (wv1 polls 32 cold tag words with s_sleep backoff -> LDS go_word),
//    then ONE poison validation; straggler chunks get a polite reload.
//  - vmask/sanitize (round-2, verified exact): out-of-block chunks never
//    retried; leftover poison -> bf16 zeros.
__global__ __launch_bounds__(256, 1) void lstm_kernel(
    const unsigned short* __restrict__ whh_f, const unsigned short* __restrict__ wih_f,
    const unsigned short* __restrict__ bias_f,
    const unsigned short* __restrict__ whh_b, const unsigned short* __restrict__ wih_b,
    const unsigned short* __restrict__ bias_b,
    const unsigned short* __restrict__ x,
    unsigned short* __restrict__ hf, unsigned short* __restrict__ hb,
    unsigned int* __restrict__ tags) {
  const int tid = threadIdx.x;
  const int wv = tid >> 6, lane = tid & 63, q = lane >> 4, l15 = lane & 15;
  const int bid = blockIdx.x;
  const int dir = bid & 1;
  const int wg = bid >> 1;            // 0..31 within direction
  const int u0 = wg * 16;

  const unsigned short* whh = dir ? whh_b : whh_f;
  const unsigned short* wih = dir ? wih_b : wih_f;
  const unsigned short* bvec = dir ? bias_b : bias_f;
  unsigned short* hbuf = dir ? hb : hf;
  unsigned int* tbase = tags + (size_t)dir * 512;  // 32 tags, 16-dword stride

  // ---- preload weight A-fragments: afrag[gate mt][k-chunk kl]
  bf16x8 afrag[4][6];
#pragma unroll
  for (int mt = 0; mt < 4; mt++) {
    int row = mt * H_ + u0 + l15;
#pragma unroll
    for (int kl = 0; kl < 6; kl++) {
      const unsigned short* p = (kl < 4)
          ? (whh + (size_t)row * H_ + (wv * 4 + kl) * 32 + q * 8)
          : (wih + (size_t)row * E_ + (wv * 2 + (kl - 4)) * 32 + q * 8);
      afrag[mt][kl] = *(const bf16x8*)p;
    }
  }

  const int eb = tid & 63;
  const int uu = tid >> 6;
  float bg[4][4];
#pragma unroll
  for (int s = 0; s < 4; s++) {
    int u = uu + 4 * s;
#pragma unroll
    for (int g = 0; g < 4; g++) bg[s][g] = bf2f(bvec[g * H_ + u0 + u]);
  }
  float cst[4] = {0.f, 0.f, 0.f, 0.f};

  __shared__ float pacc[4][64][66];
  __shared__ __align__(16) unsigned short h_out[64][16];
  __shared__ unsigned int go_word;
  if (tid == 0) go_word = 0;

  i32x4 bxw[8];
  // prologue: stage x for step 0
  ISSUE_BX(dir ? (T_ - 1) : 0);

  for (int step = 0; step < T_; step++) {
    const int t = dir ? (T_ - 1 - step) : step;
    f32x4 acc[4][4];
#pragma unroll
    for (int mt = 0; mt < 4; mt++)
#pragma unroll
      for (int nt = 0; nt < 4; nt++) acc[mt][nt] = (f32x4){0.f, 0.f, 0.f, 0.f};

    i32x4 hr4[16];
    const unsigned int* gab[4];
    const unsigned int* hD = nullptr;

    if (step > 0) {
      // speculative gather — issued once, flies during x-part + tag poll
      const int tprev = dir ? (t + 1) : (t - 1);
      hD = (const unsigned int*)hbuf + (size_t)tprev * 16384;
      gab[0] = hD + ((wv * 4 + 0) * 4 + q) * 256 + l15 * 4;
      gab[1] = hD + ((wv * 4 + 1) * 4 + q) * 256 + l15 * 4;
      gab[2] = hD + ((wv * 4 + 2) * 4 + q) * 256 + l15 * 4;
      gab[3] = hD + ((wv * 4 + 3) * 4 + q) * 256 + l15 * 4;
      asm volatile(
          "global_load_dwordx4 %0, %16, off sc0 sc1\n\t"
          "global_load_dwordx4 %1, %16, off offset:1024 sc0 sc1\n\t"
          "global_load_dwordx4 %2, %16, off offset:2048 sc0 sc1\n\t"
          "global_load_dwordx4 %3, %16, off offset:3072 sc0 sc1\n\t"
          "global_load_dwordx4 %4, %17, off sc0 sc1\n\t"
          "global_load_dwordx4 %5, %17, off offset:1024 sc0 sc1\n\t"
          "global_load_dwordx4 %6, %17, off offset:2048 sc0 sc1\n\t"
          "global_load_dwordx4 %7, %17, off offset:3072 sc0 sc1\n\t"
          "global_load_dwordx4 %8, %18, off sc0 sc1\n\t"
          "global_load_dwordx4 %9, %18, off offset:1024 sc0 sc1\n\t"
          "global_load_dwordx4 %10, %18, off offset:2048 sc0 sc1\n\t"
          "global_load_dwordx4 %11, %18, off offset:3072 sc0 sc1\n\t"
          "global_load_dwordx4 %12, %19, off sc0 sc1\n\t"
          "global_load_dwordx4 %13, %19, off offset:1024 sc0 sc1\n\t"
          "global_load_dwordx4 %14, %19, off offset:2048 sc0 sc1\n\t"
          "global_load_dwordx4 %15, %19, off offset:3072 sc0 sc1"
          : "=&v"(hr4[0]), "=&v"(hr4[1]), "=&v"(hr4[2]), "=&v"(hr4[3]),
            "=&v"(hr4[4]), "=&v"(hr4[5]), "=&v"(hr4[6]), "=&v"(hr4[7]),
            "=&v"(hr4[8]), "=&v"(hr4[9]), "=&v"(hr4[10]), "=&v"(hr4[11]),
            "=&v"(hr4[12]), "=&v"(hr4[13]), "=&v"(hr4[14]), "=&v"(hr4[15])
          : "v"(gab[0]), "v"(gab[1]), "v"(gab[2]), "v"(gab[3])
          : "memory");
    }

    // Wait for staged x only. In-order load retire: <=16 outstanding means
    // the 8 (oldest) bx loads are done. wv0's 3 fire-and-forget stores are
    // oldest of 27 -> also drained by vmcnt(16); that's its own publish ack
    // overlapping the gather, not on the inter-block path (tag already sent).
    if (step == 0) {
      asm volatile("s_waitcnt vmcnt(0)" ::: "memory");
    } else {
      asm volatile("s_waitcnt vmcnt(16)" ::: "memory");
    }
    __builtin_amdgcn_sched_barrier(0);  // no hoisting MFMA above the wait

    // x-part MFMAs from pre-staged fragments
#pragma unroll
    for (int kl = 0; kl < 2; kl++) {
#pragma unroll
      for (int nt = 0; nt < 4; nt++) {
        bf16x8 b_;
        __builtin_memcpy(&b_, &bxw[kl * 4 + nt], 16);
#pragma unroll
        for (int mt = 0; mt < 4; mt++)
          acc[mt][nt] = MFMA16(afrag[mt][4 + kl], b_, acc[mt][nt]);
      }
    }

    if (step > 0) {
      __builtin_amdgcn_sched_barrier(0);  // keep x-MFMAs above the gate

      // ---- cheap tag gate (cold 4 KB region; no data read-storm)
      if (wv == 1) {  // poller: all 32 tags in one 32-lane device load
        const unsigned int* tp = tbase + (size_t)(lane & 31) * 16;
        for (;;) {
          unsigned int v = load_dw_dev(tp);
          unsigned long long m = __ballot((lane < 32) ? (v >= (unsigned)step) : 1);
          if (m == ~0ULL) break;
          __builtin_amdgcn_s_sleep(1);
        }
        __hip_atomic_store(&go_word, (unsigned int)step, __ATOMIC_RELAXED,
                           __HIP_MEMORY_SCOPE_WORKGROUP);
      } else {        // siblings spin on LDS (no fabric traffic)
        while (__hip_atomic_load(&go_word, __ATOMIC_RELAXED,
                                 __HIP_MEMORY_SCOPE_WORKGROUP) < (unsigned int)step)
          __builtin_amdgcn_s_sleep(1);
      }
      asm volatile("" ::: "memory");

      // retry-eligibility mask (wave-uniform): only fully in-block chunks
      unsigned int vmask = 0;
#pragma unroll
      for (int c = 0; c < 16; c++) {
        const unsigned int* ap = gab[c >> 2] + (c & 3) * 256;
        int oob = (ap < hD) | ((ap + 4) > (hD + 16384));
        if (__ballot(oob) == 0ULL) vmask |= (1u << c);
      }

      // ---- ONE poison validation; stragglers reloaded politely.
      // Tag >= step guarantees the producer issued its stores -> eventual
      // visibility -> retry terminates.
      asm volatile("s_waitcnt vmcnt(0)" ::: "memory");
      __builtin_amdgcn_sched_barrier(0);
      for (;;) {
        unsigned int pend = 0;
#pragma unroll
        for (int c = 0; c < 16; c++) {
          int bad = (hr4[c][0] == -1) | (hr4[c][1] == -1) |
                    (hr4[c][2] == -1) | (hr4[c][3] == -1);
          if (__ballot(bad) != 0ULL) pend |= (1u << c);
        }
        pend &= vmask;
        if (!pend) break;
        __builtin_amdgcn_s_sleep(1);
#pragma unroll
        for (int c = 0; c < 16; c++) {
          if (pend & (1u << c)) {
            asm volatile("global_load_dwordx4 %0, %1, off sc0 sc1"
                         : "=&v"(hr4[c])
                         : "v"(gab[c >> 2] + (c & 3) * 256)
                         : "memory");
          }
        }
        asm volatile("s_waitcnt vmcnt(0)" ::: "memory");
        __builtin_amdgcn_sched_barrier(0);
      }

      // SANITIZE non-retried (out-of-block) chunks: poison -> bf16 zeros
      // (verified exact in round 2).
      unsigned int inval = (~vmask) & 0xFFFFu;
      if (inval) {
#pragma unroll
        for (int c = 0; c < 16; c++) {
          if (inval & (1u << c)) {
#pragma unroll
            for (int j = 0; j < 4; j++)
              hr4[c][j] = (hr4[c][j] == -1) ? 0 : hr4[c][j];
          }
        }
      }

      // h-part MFMAs (consumption identical to verified kernel)
#pragma unroll
      for (int kl = 0; kl < 4; kl++) {
#pragma unroll
        for (int nt = 0; nt < 4; nt++) {
          bf16x8 bh;
          __builtin_memcpy(&bh, &hr4[kl * 4 + nt], 16);
#pragma unroll
          for (int mt = 0; mt < 4; mt++)
            acc[mt][nt] = MFMA16(afrag[mt][kl], bh, acc[mt][nt]);
        }
      }
    }

    __syncthreads();
#pragma unroll
    for (int mt = 0; mt < 4; mt++)
#pragma unroll
      for (int nt = 0; nt < 4; nt++)
#pragma unroll
        for (int r = 0; r < 4; r++)
          pacc[wv][mt * 16 + q * 4 + r][nt * 16 + l15] = acc[mt][nt][r];
    __syncthreads();

    // stage x for the NEXT step now — latency hides under gate math + barrier
    if (step < T_ - 1) ISSUE_BX(dir ? (T_ - 2 - step) : (step + 1));

#pragma unroll
    for (int s = 0; s < 4; s++) {
      int u = uu + 4 * s;
      float gi = bg[s][0], gf = bg[s][1], gg = bg[s][2], og = bg[s][3];
#pragma unroll
      for (int w = 0; w < 4; w++) {
        gi += pacc[w][u][eb];
        gf += pacc[w][16 + u][eb];
        gg += pacc[w][32 + u][eb];
        og += pacc[w][48 + u][eb];
      }
      float cn = sigm(gf) * cst[s] + sigm(gi) * tanh_(gg);
      cst[s] = cn;
      h_out[eb][u] = f2bf(sigm(og) * tanh_(cn));
    }
    __syncthreads();

    if (wv == 0) {  // publish: data + tag, ALL fire-and-forget (no drain)
      unsigned int* gp = (unsigned int*)hbuf + (size_t)t * 16384 + wg * 512 + lane * 4;
      i32x4 v0 = *(const i32x4*)&h_out[lane][0];
      i32x4 v1 = *(const i32x4*)&h_out[lane][8];
      asm volatile(
          "global_store_dwordx4 %0, %1, off sc0 sc1\n\t"
          "global_store_dwordx4 %0, %2, off offset:1024 sc0 sc1"
          :: "v"(gp), "v"(v0), "v"(v1) : "memory");
      if (lane == 0) {
        unsigned int* tp = tbase + (size_t)wg * 16;
        unsigned int tv = (unsigned int)(step + 1);
        asm volatile("global_store_dword %0, %1, off sc0 sc1"
                     :: "v"(tp), "v"(tv) : "memory");
      }
    }
  }
}

// ---------------------------------------------------------------- encoder GEMM
// states = tanh([hf|hb] @ w_enc^T + b_enc): M=32768, K=1024, N=512.
__global__ __launch_bounds__(256) void enc_kernel(
    const unsigned short* __restrict__ hf, const unsigned short* __restrict__ hb,
    const unsigned short* __restrict__ w_enc, const unsigned short* __restrict__ b_enc,
    unsigned short* __restrict__ states) {
  const int tid = threadIdx.x;
  const int bm = blockIdx.x, bn = blockIdx.y;
  const int wv = tid >> 6, lane = tid & 63, q = lane >> 4, l15 = lane & 15;
  const int wm = wv >> 1, wn = wv & 1;

  __shared__ __align__(16) unsigned short a_lds[128][72];
  __shared__ __align__(16) unsigned short b_lds[128][72];
  __shared__ __align__(16) unsigned short st_lds[128][136];

  f32x4 acc[4][4];
#pragma unroll
  for (int mt = 0; mt < 4; mt++)
#pragma unroll
    for (int nt = 0; nt < 4; nt++) acc[mt][nt] = (f32x4){0.f, 0.f, 0.f, 0.f};

  for (int c = 0; c < 16; c++) {
    const unsigned short* asrc = (c < 8) ? hf : hb;
    int kof = (c & 7) * 64;
#pragma unroll
    for (int p = 0; p < 4; p++) {
      int u_ = tid + p * 256;
      int r = u_ >> 3, wu = u_ & 7;
      int grow = bm * 128 + r;   // t = grow>>6, b = grow&63
      *(i32x4*)&a_lds[r][wu * 8] =
          *(const i32x4*)((const unsigned int*)asrc + (size_t)(grow >> 6) * 16384 +
                          (size_t)((kof >> 3) + wu) * 256 + (grow & 63) * 4);
      *(i32x4*)&b_lds[r][wu * 8] =
          *(const i32x4*)(w_enc + (size_t)(bn * 128 + r) * 1024 + c * 64 + wu * 8);
    }
    __syncthreads();
#pragma unroll
    for (int kk = 0; kk < 64; kk += 32) {
      bf16x8 af[4], bfr[4];
#pragma unroll
      for (int mt = 0; mt < 4; mt++)
        af[mt] = *(const bf16x8*)&a_lds[wm * 64 + mt * 16 + l15][kk + q * 8];
#pragma unroll
      for (int nt = 0; nt < 4; nt++)
        bfr[nt] = *(const bf16x8*)&b_lds[wn * 64 + nt * 16 + l15][kk + q * 8];
#pragma unroll
      for (int mt = 0; mt < 4; mt++)
#pragma unroll
        for (int nt = 0; nt < 4; nt++) acc[mt][nt] = MFMA16(af[mt], bfr[nt], acc[mt][nt]);
    }
    __syncthreads();
  }

  float be[4];
#pragma unroll
  for (int nt = 0; nt < 4; nt++)
    be[nt] = bf2f(b_enc[bn * 128 + wn * 64 + nt * 16 + l15]);
#pragma unroll
  for (int mt = 0; mt < 4; mt++)
#pragma unroll
    for (int nt = 0; nt < 4; nt++)
#pragma unroll
      for (int r = 0; r < 4; r++) {
        float v = tanh_(acc[mt][nt][r] + be[nt]);
        st_lds[wm * 64 + mt * 16 + q * 4 + r][wn * 64 + nt * 16 + l15] = f2bf(v);
      }
  __syncthreads();
#pragma unroll
  for (int p = 0; p < 8; p++) {
    int u_ = tid + p * 256;
    int r = u_ >> 4, w = u_ & 15;
    *(i32x4*)(states + (size_t)(bm * 128 + r) * H_ + bn * 128 + w * 8) =
        *(const i32x4*)&st_lds[r][w * 8];
  }
}

// ---------------------------------------------------------------- emit GEMM
// emit = states @ w_out^T + b_out: M=32768, K=512, N=50 (padded 64), fp32 out
__global__ __launch_bounds__(256) void emit_kernel(
    const unsigned short* __restrict__ states, const unsigned short* __restrict__ w_out,
    const unsigned short* __restrict__ b_out, float* __restrict__ emit) {
  const int tid = threadIdx.x;
  const int bm = blockIdx.x;
  const int wv = tid >> 6, lane = tid & 63, q = lane >> 4, l15 = lane & 15;
  const int wm = wv >> 1, wn = wv & 1;

  __shared__ __align__(16) unsigned short wo_lds[64][520];
  __shared__ __align__(16) unsigned short a_lds[128][72];

#pragma unroll
  for (int p = 0; p < 16; p++) {
    int u = tid + p * 256;
    int r = u >> 6, wu = u & 63;
    i32x4 v = {0, 0, 0, 0};
    if (r < KT) v = *(const i32x4*)(w_out + (size_t)r * H_ + wu * 8);
    *(i32x4*)&wo_lds[r][wu * 8] = v;
  }

  f32x4 acc[4][2];
#pragma unroll
  for (int mt = 0; mt < 4; mt++)
#pragma unroll
    for (int nt = 0; nt < 2; nt++) acc[mt][nt] = (f32x4){0.f, 0.f, 0.f, 0.f};

  for (int c = 0; c < 8; c++) {
    __syncthreads();
#pragma unroll
    for (int p = 0; p < 4; p++) {
      int u = tid + p * 256;
      int r = u >> 3, wu = u & 7;
      *(i32x4*)&a_lds[r][wu * 8] =
          *(const i32x4*)(states + (size_t)(bm * 128 + r) * H_ + c * 64 + wu * 8);
    }
    __syncthreads();
#pragma unroll
    for (int kk = 0; kk < 64; kk += 32) {
      bf16x8 af[4], bfr[2];
#pragma unroll
      for (int mt = 0; mt < 4; mt++)
        af[mt] = *(const bf16x8*)&a_lds[wm * 64 + mt * 16 + l15][kk + q * 8];
#pragma unroll
      for (int nt = 0; nt < 2; nt++)
        bfr[nt] = *(const bf16x8*)&wo_lds[wn * 32 + nt * 16 + l15][c * 64 + kk + q * 8];
#pragma unroll
      for (int mt = 0; mt < 4; mt++)
#pragma unroll
        for (int nt = 0; nt < 2; nt++) acc[mt][nt] = MFMA16(af[mt], bfr[nt], acc[mt][nt]);
    }
  }

  float bo[2];
#pragma unroll
  for (int nt = 0; nt < 2; nt++) {
    int n = wn * 32 + nt * 16 + l15;
    bo[nt] = (n < KT) ? bf2f(b_out[n]) : 0.f;
  }
#pragma unroll
  for (int mt = 0; mt < 4; mt++)
#pragma unroll
    for (int nt = 0; nt < 2; nt++) {
      int n = wn * 32 + nt * 16 + l15;
      if (n < KT) {
#pragma unroll
        for (int r = 0; r < 4; r++) {
          int m = bm * 128 + wm * 64 + mt * 16 + q * 4 + r;
          emit[(size_t)m * KT + n] = acc[mt][nt][r] + bo[nt];
        }
      }
    }
}

// ---------------------------------------------------------------- CRF forward
__global__ __launch_bounds__(256) void crf_kernel(
    const float* __restrict__ emit, const unsigned short* __restrict__ trans,
    const unsigned int* __restrict__ flag, void* __restrict__ out) {
  const int tid = threadIdx.x;
  const int wv = tid >> 6, lane = tid & 63;
  const int b = blockIdx.x * 4 + wv;
  const int jj = (lane < KT) ? lane : (KT - 1);

  float tr[KT];
  float mj = -1e30f;
#pragma unroll
  for (int i = 0; i < KT; i++) {
    tr[i] = bf2f(trans[jj * KT + i]);
    mj = fmaxf(mj, tr[i]);
  }
  float et[KT];
#pragma unroll
  for (int i = 0; i < KT; i++) et[i] = __expf(tr[i] - mj);
  float tr_stop = bf2f(trans[(KT - 1) * KT + jj]);

  float alpha = (lane == 0) ? 0.f : -1e30f;
  float e_next = emit[(size_t)b * KT + jj];

  for (int t = 0; t < T_; t++) {
    float e_cur = e_next;
    if (t < T_ - 1) e_next = emit[((size_t)(t + 1) * B_ + b) * KT + jj];
    float M = alpha;
#pragma unroll
    for (int off = 32; off; off >>= 1) M = fmaxf(M, __shfl_xor(M, off, 64));
    float p = __expf(alpha - M);
    float s = 0.f;
#pragma unroll
    for (int i = 0; i < KT; i++) {
      float pi = __uint_as_float(__builtin_amdgcn_readlane(__float_as_uint(p), i));
      s = __builtin_fmaf(et[i], pi, s);
    }
    float an = e_cur + mj + M + __logf(s);
    alpha = (lane < KT) ? an : -1e30f;
  }

  float v = (lane < KT) ? (alpha + tr_stop) : -1e30f;
  float M2 = v;
#pragma unroll
  for (int off = 32; off; off >>= 1) M2 = fmaxf(M2, __shfl_xor(M2, off, 64));
  float s2 = (lane < KT) ? __expf(v - M2) : 0.f;
#pragma unroll
  for (int off = 32; off; off >>= 1) s2 += __shfl_xor(s2, off, 64);
  float lz = M2 + __logf(s2);
  if (lane == 0) {
    if (*flag) ((unsigned short*)out)[b] = f2bf(lz);
    else ((float*)out)[b] = lz;
  }
}

// ---------------------------------------------------------------- launch
extern "C" void kernel_launch(void* const* d_in, const int* in_sizes, int n_in,
                              void* d_out, int out_size, void* d_ws, size_t ws_size,
                              hipStream_t stream) {
  const int* tokens = (const int*)d_in[0];
  const void* embed = d_in[1];
  const void* wih_f = d_in[2];
  const void* whh_f = d_in[3];
  const void* b_f = d_in[4];
  const void* wih_b = d_in[5];
  const void* whh_b = d_in[6];
  const void* b_b = d_in[7];
  const void* w_enc = d_in[8];
  const void* b_enc = d_in[9];
  const void* w_out = d_in[10];
  const void* b_out = d_in[11];
  const void* trans = d_in[12];

  char* ws = (char*)d_ws;
  // tags: [dir][wg] monotonic words, 16-dword (64B) stride = 4 KB total
  unsigned int* tags = (unsigned int*)ws;
  unsigned int* pflag = (unsigned int*)(ws + 262144);            // 256 B
  unsigned short* xbuf = (unsigned short*)(ws + 262400);         // 16 MB
  unsigned short* hf = (unsigned short*)(ws + 17039616);         // 32 MB
  unsigned short* hb = (unsigned short*)(ws + 50594048);         // 32 MB (contig after hf)
  unsigned short* states = (unsigned short*)(ws + 84148480);     // 32 MB
  float* emit = (float*)(ws + 117702912);                        // 6.55 MB
  unsigned short* canon = (unsigned short*)(ws + 124256512);     // 7.4 MB

  unsigned short* c_wih_f = canon + 0;
  unsigned short* c_whh_f = canon + 524288;
  unsigned short* c_b_f   = canon + 1572864;
  unsigned short* c_wih_b = canon + 1574912;
  unsigned short* c_whh_b = canon + 2099200;
  unsigned short* c_b_b   = canon + 3147776;
  unsigned short* c_w_enc = canon + 3149824;
  unsigned short* c_b_enc = canon + 3674112;
  unsigned short* c_w_out = canon + 3674624;
  unsigned short* c_b_out = canon + 3700224;
  unsigned short* c_trans = canon + 3700352;

  hipMemsetAsync(tags, 0, 4096, stream);
  probe_kernel<<<1, 64, 0, stream>>>((const unsigned short*)embed, pflag);

  CvtPack pk;
  pk.a[0]  = {wih_f, c_wih_f, 524288};
  pk.a[1]  = {whh_f, c_whh_f, 1048576};
  pk.a[2]  = {b_f,   c_b_f,   2048};
  pk.a[3]  = {wih_b, c_wih_b, 524288};
  pk.a[4]  = {whh_b, c_whh_b, 1048576};
  pk.a[5]  = {b_b,   c_b_b,   2048};
  pk.a[6]  = {w_enc, c_w_enc, 524288};
  pk.a[7]  = {b_enc, c_b_enc, 512};
  pk.a[8]  = {w_out, c_w_out, 25600};
  pk.a[9]  = {b_out, c_b_out, 50};
  pk.a[10] = {trans, c_trans, 2500};
  convert_kernel<<<dim3(512, 11), 256, 0, stream>>>(pk, pflag);

  embed_kernel<<<(T_ * B_) / 8, 256, 0, stream>>>(tokens, embed, pflag, xbuf);
  // re-poison h buffers every launch; 2048 blocks x 32 KB = 64 MB (hf|hb)
  poison_kernel<<<2048, 256, 0, stream>>>((unsigned int*)(ws + 17039616));
  lstm_kernel<<<64, 256, 0, stream>>>(c_whh_f, c_wih_f, c_b_f,
                                      c_whh_b, c_wih_b, c_b_b,
                                      xbuf, hf, hb, tags);
  enc_kernel<<<dim3(256, 4), 256, 0, stream>>>(hf, hb, c_w_enc, c_b_enc, states);
  emit_kernel<<<256, 256, 0, stream>>>(states, c_w_out, c_b_out, emit);
  crf_kernel<<<16, 256, 0, stream>>>(emit, c_trans, pflag, d_out);
}

// Round 4
// 2892.177 us; speedup vs baseline: 1.6821x; 1.6821x over previous
//
#include <hip/hip_runtime.h>
#include <stdint.h>

#define T_ 512
#define B_ 64
#define E_ 256
#define H_ 512
#define KT 50

typedef __attribute__((ext_vector_type(8))) short bf16x8;
typedef __attribute__((ext_vector_type(4))) float f32x4;
typedef __attribute__((ext_vector_type(4))) int i32x4;

#define MFMA16(a,b,c) __builtin_amdgcn_mfma_f32_16x16x32_bf16((a),(b),(c),0,0,0)

static __device__ __forceinline__ float bf2f(unsigned short v) {
  unsigned int u = ((unsigned int)v) << 16; float f; __builtin_memcpy(&f, &u, 4); return f;
}
static __device__ __forceinline__ unsigned short f2bf(float f) {
  unsigned int u; __builtin_memcpy(&u, &f, 4);
  u += 0x7fffu + ((u >> 16) & 1u);
  return (unsigned short)(u >> 16);
}
static __device__ __forceinline__ float sigm(float x) { return 1.f / (1.f + __expf(-x)); }
static __device__ __forceinline__ float tanh_(float x) { return 2.f / (1.f + __expf(-2.f * x)) - 1.f; }

// device-scope (MALL) dword load, self-waiting — for single-word tag polls
static __device__ __forceinline__ unsigned int load_dw_dev(const unsigned int* p) {
  unsigned int v;
  asm volatile("global_load_dword %0, %1, off sc0 sc1\n\ts_waitcnt vmcnt(0)"
               : "=v"(v) : "v"(p) : "memory");
  return v;
}

// ------------------------------------------------------------- dtype probe
__global__ void probe_kernel(const unsigned short* __restrict__ e,
                             unsigned int* __restrict__ flag) {
  int lane = threadIdx.x & 63;
  float a = fabsf(bf2f(e[2 * lane]));
  int good = (a >= 1e-8f && a <= 4.0f);
  unsigned long long m = __ballot(good);
  if (threadIdx.x == 0) flag[0] = (__popcll(m) >= 48) ? 1u : 0u;
}

// ------------------------------------------------------------- canonicalize
struct CvtArgs { const void* src; unsigned short* dst; int n; };
struct CvtPack { CvtArgs a[11]; };

__global__ __launch_bounds__(256) void convert_kernel(CvtPack p,
                                                      const unsigned int* __restrict__ flag) {
  CvtArgs c = p.a[blockIdx.y];
  int i = (blockIdx.x * 256 + threadIdx.x) * 8;
  if (i >= c.n) return;
  int isbf = *flag;
  if (i + 8 <= c.n) {
    if (isbf) {
      *(i32x4*)(c.dst + i) = *(const i32x4*)((const unsigned short*)c.src + i);
    } else {
      const float* s = (const float*)c.src;
      float4 a0 = *(const float4*)(s + i);
      float4 a1 = *(const float4*)(s + i + 4);
      unsigned short o[8] = {f2bf(a0.x), f2bf(a0.y), f2bf(a0.z), f2bf(a0.w),
                             f2bf(a1.x), f2bf(a1.y), f2bf(a1.z), f2bf(a1.w)};
      *(i32x4*)(c.dst + i) = *(i32x4*)o;
    }
  } else {
    for (int j = 0; j < 8; j++) {
      if (i + j < c.n) {
        c.dst[i + j] = isbf ? ((const unsigned short*)c.src)[i + j]
                            : f2bf(((const float*)c.src)[i + j]);
      }
    }
  }
}

// ---------------------------------------------------------------- embedding
__global__ __launch_bounds__(256) void embed_kernel(
    const int* __restrict__ tokens, const void* __restrict__ embed,
    const unsigned int* __restrict__ flag, unsigned short* __restrict__ x) {
  int tid = threadIdx.x;
  int row = blockIdx.x * 8 + (tid >> 5);   // row = t*64+b, 32768 rows
  int l = tid & 31;
  int tok = tokens[row];
  if (*flag) {
    const unsigned short* e = (const unsigned short*)embed;
    *(i32x4*)(x + (size_t)row * E_ + l * 8) =
        *(const i32x4*)(e + (size_t)tok * E_ + l * 8);
  } else {
    const float* e = (const float*)embed + (size_t)tok * E_ + l * 8;
    float4 a0 = *(const float4*)e;
    float4 a1 = *(const float4*)(e + 4);
    unsigned short o[8] = {f2bf(a0.x), f2bf(a0.y), f2bf(a0.z), f2bf(a0.w),
                           f2bf(a1.x), f2bf(a1.y), f2bf(a1.z), f2bf(a1.w)};
    *(i32x4*)(x + (size_t)row * E_ + l * 8) = *(i32x4*)o;
  }
}

// x-staging: 8 dwordx4 loads for one timestep, issued a step early so the
// HBM/L2 latency hides under gate math + publish + next step's tag wait.
// Exactness of this staging+consumption verified in rounds 2/3.
#define ISSUE_BX(tt)                                                          \
  do {                                                                        \
    const unsigned short* xb_ = x + (size_t)(tt) * (B_ * E_);                 \
    const unsigned short* x0_ = xb_ + (size_t)(0 * 16 + l15) * E_ + (wv * 2 + 0) * 32 + q * 8; \
    const unsigned short* x1_ = xb_ + (size_t)(1 * 16 + l15) * E_ + (wv * 2 + 0) * 32 + q * 8; \
    const unsigned short* x2_ = xb_ + (size_t)(2 * 16 + l15) * E_ + (wv * 2 + 0) * 32 + q * 8; \
    const unsigned short* x3_ = xb_ + (size_t)(3 * 16 + l15) * E_ + (wv * 2 + 0) * 32 + q * 8; \
    const unsigned short* x4_ = xb_ + (size_t)(0 * 16 + l15) * E_ + (wv * 2 + 1) * 32 + q * 8; \
    const unsigned short* x5_ = xb_ + (size_t)(1 * 16 + l15) * E_ + (wv * 2 + 1) * 32 + q * 8; \
    const unsigned short* x6_ = xb_ + (size_t)(2 * 16 + l15) * E_ + (wv * 2 + 1) * 32 + q * 8; \
    const unsigned short* x7_ = xb_ + (size_t)(3 * 16 + l15) * E_ + (wv * 2 + 1) * 32 + q * 8; \
    asm volatile(                                                             \
        "global_load_dwordx4 %0, %8, off\n\t"                                 \
        "global_load_dwordx4 %1, %9, off\n\t"                                 \
        "global_load_dwordx4 %2, %10, off\n\t"                                \
        "global_load_dwordx4 %3, %11, off\n\t"                                \
        "global_load_dwordx4 %4, %12, off\n\t"                                \
        "global_load_dwordx4 %5, %13, off\n\t"                                \
        "global_load_dwordx4 %6, %14, off\n\t"                                \
        "global_load_dwordx4 %7, %15, off"                                    \
        : "=&v"(bxw[0]), "=&v"(bxw[1]), "=&v"(bxw[2]), "=&v"(bxw[3]),         \
          "=&v"(bxw[4]), "=&v"(bxw[5]), "=&v"(bxw[6]), "=&v"(bxw[7])          \
        : "v"(x0_), "v"(x1_), "v"(x2_), "v"(x3_),                             \
          "v"(x4_), "v"(x5_), "v"(x6_), "v"(x7_)                              \
        : "memory");                                                          \
  } while (0)

// ---------------------------------------------------------------- BiLSTM
// 64 blocks: dir = bid&1, wg = bid>>1. Weights pinned in VGPRs. Publish and
// gather ADDRESSES byte-identical to the harness-verified round-0 kernel.
// Transport = round-0 semantics (verified): publish 2 stores + vmcnt(0)
// drain, THEN monotonic tag store -> tag visible implies data visible.
//
// Round-4 changes (within verified semantics):
//  1. PER-WAVE tag gate: wave wv's gather touches only slabs written by
//     producers wg = wv*8 .. wv*8+9 (clamped; derived from gather address
//     range, and round-2/3 sanitize proved out-of-range slabs contribute
//     nothing). Each wave polls its own <=10 tags -> removes the single
//     poller + LDS go_word broadcast + sibling wakeup, and shrinks the
//     straggler wait from max-of-32 to max-of-10.
//  2. Gather issued at tag-fire, x-MFMAs run under it, then one vmcnt(0).
//  3. x fragments prestaged one step early (ISSUE_BX) under counted waits:
//     wv0's publish drain already retired its x loads -> vmcnt(1) (tag
//     store may be in flight); other waves vmcnt(0) (only 8 x loads out).
__global__ __launch_bounds__(256, 1) void lstm_kernel(
    const unsigned short* __restrict__ whh_f, const unsigned short* __restrict__ wih_f,
    const unsigned short* __restrict__ bias_f,
    const unsigned short* __restrict__ whh_b, const unsigned short* __restrict__ wih_b,
    const unsigned short* __restrict__ bias_b,
    const unsigned short* __restrict__ x,
    unsigned short* __restrict__ hf, unsigned short* __restrict__ hb,
    unsigned int* __restrict__ tags) {
  const int tid = threadIdx.x;
  const int wv = tid >> 6, lane = tid & 63, q = lane >> 4, l15 = lane & 15;
  const int bid = blockIdx.x;
  const int dir = bid & 1;
  const int wg = bid >> 1;            // 0..31 within direction
  const int u0 = wg * 16;

  const unsigned short* whh = dir ? whh_b : whh_f;
  const unsigned short* wih = dir ? wih_b : wih_f;
  const unsigned short* bvec = dir ? bias_b : bias_f;
  unsigned short* hbuf = dir ? hb : hf;
  unsigned int* tbase = tags + (size_t)dir * 512;  // 32 tags, 16-dword stride

  // ---- preload weight A-fragments: afrag[gate mt][k-chunk kl]
  bf16x8 afrag[4][6];
#pragma unroll
  for (int mt = 0; mt < 4; mt++) {
    int row = mt * H_ + u0 + l15;
#pragma unroll
    for (int kl = 0; kl < 6; kl++) {
      const unsigned short* p = (kl < 4)
          ? (whh + (size_t)row * H_ + (wv * 4 + kl) * 32 + q * 8)
          : (wih + (size_t)row * E_ + (wv * 2 + (kl - 4)) * 32 + q * 8);
      afrag[mt][kl] = *(const bf16x8*)p;
    }
  }

  // per-wave producer-tag pointer: producers wv*8 .. wv*8+9 (clamped to 31)
  int poff = (l15 < 10) ? l15 : 0;
  int pidx = wv * 8 + poff;
  if (pidx > 31) pidx = 31;
  const unsigned int* my_tp = tbase + (size_t)pidx * 16;

  const int eb = tid & 63;
  const int uu = tid >> 6;
  float bg[4][4];
#pragma unroll
  for (int s = 0; s < 4; s++) {
    int u = uu + 4 * s;
#pragma unroll
    for (int g = 0; g < 4; g++) bg[s][g] = bf2f(bvec[g * H_ + u0 + u]);
  }
  float cst[4] = {0.f, 0.f, 0.f, 0.f};

  __shared__ float pacc[4][64][66];
  __shared__ __align__(16) unsigned short h_out[64][16];

  i32x4 bxw[8];
  // prologue: stage x for step 0
  ISSUE_BX(dir ? (T_ - 1) : 0);

  for (int step = 0; step < T_; step++) {
    const int t = dir ? (T_ - 1 - step) : step;
    f32x4 acc[4][4];
#pragma unroll
    for (int mt = 0; mt < 4; mt++)
#pragma unroll
      for (int nt = 0; nt < 4; nt++) acc[mt][nt] = (f32x4){0.f, 0.f, 0.f, 0.f};

    // ---- x-wait (counted; see header comment)
    if (step == 0) {
      asm volatile("s_waitcnt vmcnt(0)" ::: "memory");
    } else if (wv == 0) {
      asm volatile("s_waitcnt vmcnt(1)" ::: "memory");  // tag store residue
    } else {
      asm volatile("s_waitcnt vmcnt(0)" ::: "memory");
    }
    __builtin_amdgcn_sched_barrier(0);

    i32x4 hr4[16];
    if (step > 0) {
      // ---- per-wave tag gate (cold region, <=10 unique dwords, backoff)
      for (;;) {
        unsigned int v = load_dw_dev(my_tp);
        if (__ballot(v >= (unsigned)step) == ~0ULL) break;
        __builtin_amdgcn_s_sleep(1);
      }
      asm volatile("" ::: "memory");  // no hoisting of gather above the gate

      // ---- gather: issue 16 device-scope loads, NO wait yet
      const int tprev = dir ? (t + 1) : (t - 1);
      const unsigned int* hD = (const unsigned int*)hbuf + (size_t)tprev * 16384;
      const unsigned int* a0 = hD + ((wv * 4 + 0) * 4 + q) * 256 + l15 * 4;
      const unsigned int* a1 = hD + ((wv * 4 + 1) * 4 + q) * 256 + l15 * 4;
      const unsigned int* a2 = hD + ((wv * 4 + 2) * 4 + q) * 256 + l15 * 4;
      const unsigned int* a3 = hD + ((wv * 4 + 3) * 4 + q) * 256 + l15 * 4;
      asm volatile(
          "global_load_dwordx4 %0, %16, off sc0 sc1\n\t"
          "global_load_dwordx4 %1, %16, off offset:1024 sc0 sc1\n\t"
          "global_load_dwordx4 %2, %16, off offset:2048 sc0 sc1\n\t"
          "global_load_dwordx4 %3, %16, off offset:3072 sc0 sc1\n\t"
          "global_load_dwordx4 %4, %17, off sc0 sc1\n\t"
          "global_load_dwordx4 %5, %17, off offset:1024 sc0 sc1\n\t"
          "global_load_dwordx4 %6, %17, off offset:2048 sc0 sc1\n\t"
          "global_load_dwordx4 %7, %17, off offset:3072 sc0 sc1\n\t"
          "global_load_dwordx4 %8, %18, off sc0 sc1\n\t"
          "global_load_dwordx4 %9, %18, off offset:1024 sc0 sc1\n\t"
          "global_load_dwordx4 %10, %18, off offset:2048 sc0 sc1\n\t"
          "global_load_dwordx4 %11, %18, off offset:3072 sc0 sc1\n\t"
          "global_load_dwordx4 %12, %19, off sc0 sc1\n\t"
          "global_load_dwordx4 %13, %19, off offset:1024 sc0 sc1\n\t"
          "global_load_dwordx4 %14, %19, off offset:2048 sc0 sc1\n\t"
          "global_load_dwordx4 %15, %19, off offset:3072 sc0 sc1"
          : "=&v"(hr4[0]), "=&v"(hr4[1]), "=&v"(hr4[2]), "=&v"(hr4[3]),
            "=&v"(hr4[4]), "=&v"(hr4[5]), "=&v"(hr4[6]), "=&v"(hr4[7]),
            "=&v"(hr4[8]), "=&v"(hr4[9]), "=&v"(hr4[10]), "=&v"(hr4[11]),
            "=&v"(hr4[12]), "=&v"(hr4[13]), "=&v"(hr4[14]), "=&v"(hr4[15])
          : "v"(a0), "v"(a1), "v"(a2), "v"(a3)
          : "memory");
    }

    // ---- x-part MFMAs (register-only; hide the gather RT under them)
#pragma unroll
    for (int kl = 0; kl < 2; kl++) {
#pragma unroll
      for (int nt = 0; nt < 4; nt++) {
        bf16x8 b_;
        __builtin_memcpy(&b_, &bxw[kl * 4 + nt], 16);
#pragma unroll
        for (int mt = 0; mt < 4; mt++)
          acc[mt][nt] = MFMA16(afrag[mt][4 + kl], b_, acc[mt][nt]);
      }
    }

    if (step > 0) {
      asm volatile("s_waitcnt vmcnt(0)" ::: "memory");  // gather complete
      __builtin_amdgcn_sched_barrier(0);

      // ---- h-part MFMAs (consumption identical to verified kernel)
#pragma unroll
      for (int kl = 0; kl < 4; kl++) {
#pragma unroll
        for (int nt = 0; nt < 4; nt++) {
          bf16x8 bh;
          __builtin_memcpy(&bh, &hr4[kl * 4 + nt], 16);
#pragma unroll
          for (int mt = 0; mt < 4; mt++)
            acc[mt][nt] = MFMA16(afrag[mt][kl], bh, acc[mt][nt]);
        }
      }
    }

    __syncthreads();
#pragma unroll
    for (int mt = 0; mt < 4; mt++)
#pragma unroll
      for (int nt = 0; nt < 4; nt++)
#pragma unroll
        for (int r = 0; r < 4; r++)
          pacc[wv][mt * 16 + q * 4 + r][nt * 16 + l15] = acc[mt][nt][r];
    __syncthreads();

    // stage x for the NEXT step now — latency hides under gate math +
    // publish + next step's tag wait
    if (step < T_ - 1) ISSUE_BX(dir ? (T_ - 2 - step) : (step + 1));

#pragma unroll
    for (int s = 0; s < 4; s++) {
      int u = uu + 4 * s;
      float gi = bg[s][0], gf = bg[s][1], gg = bg[s][2], og = bg[s][3];
#pragma unroll
      for (int w = 0; w < 4; w++) {
        gi += pacc[w][u][eb];
        gf += pacc[w][16 + u][eb];
        gg += pacc[w][32 + u][eb];
        og += pacc[w][48 + u][eb];
      }
      float cn = sigm(gf) * cst[s] + sigm(gi) * tanh_(gg);
      cst[s] = cn;
      h_out[eb][u] = f2bf(sigm(og) * tanh_(cn));
    }
    __syncthreads();

    if (wv == 0) {  // publish: 2 vec stores + one drain, then tag (monotonic)
      unsigned int* gp = (unsigned int*)hbuf + (size_t)t * 16384 + wg * 512 + lane * 4;
      i32x4 v0 = *(const i32x4*)&h_out[lane][0];
      i32x4 v1 = *(const i32x4*)&h_out[lane][8];
      asm volatile(
          "global_store_dwordx4 %0, %1, off sc0 sc1\n\t"
          "global_store_dwordx4 %0, %2, off offset:1024 sc0 sc1\n\t"
          "s_waitcnt vmcnt(0)"
          :: "v"(gp), "v"(v0), "v"(v1) : "memory");
      if (lane == 0) {
        unsigned int* tp = tbase + (size_t)wg * 16;
        unsigned int tv = (unsigned int)(step + 1);
        asm volatile("global_store_dword %0, %1, off sc0 sc1"
                     :: "v"(tp), "v"(tv) : "memory");
      }
    }
  }
}

// ---------------------------------------------------------------- encoder GEMM
// states = tanh([hf|hb] @ w_enc^T + b_enc): M=32768, K=1024, N=512.
__global__ __launch_bounds__(256) void enc_kernel(
    const unsigned short* __restrict__ hf, const unsigned short* __restrict__ hb,
    const unsigned short* __restrict__ w_enc, const unsigned short* __restrict__ b_enc,
    unsigned short* __restrict__ states) {
  const int tid = threadIdx.x;
  const int bm = blockIdx.x, bn = blockIdx.y;
  const int wv = tid >> 6, lane = tid & 63, q = lane >> 4, l15 = lane & 15;
  const int wm = wv >> 1, wn = wv & 1;

  __shared__ __align__(16) unsigned short a_lds[128][72];
  __shared__ __align__(16) unsigned short b_lds[128][72];
  __shared__ __align__(16) unsigned short st_lds[128][136];

  f32x4 acc[4][4];
#pragma unroll
  for (int mt = 0; mt < 4; mt++)
#pragma unroll
    for (int nt = 0; nt < 4; nt++) acc[mt][nt] = (f32x4){0.f, 0.f, 0.f, 0.f};

  for (int c = 0; c < 16; c++) {
    const unsigned short* asrc = (c < 8) ? hf : hb;
    int kof = (c & 7) * 64;
#pragma unroll
    for (int p = 0; p < 4; p++) {
      int u_ = tid + p * 256;
      int r = u_ >> 3, wu = u_ & 7;
      int grow = bm * 128 + r;   // t = grow>>6, b = grow&63
      *(i32x4*)&a_lds[r][wu * 8] =
          *(const i32x4*)((const unsigned int*)asrc + (size_t)(grow >> 6) * 16384 +
                          (size_t)((kof >> 3) + wu) * 256 + (grow & 63) * 4);
      *(i32x4*)&b_lds[r][wu * 8] =
          *(const i32x4*)(w_enc + (size_t)(bn * 128 + r) * 1024 + c * 64 + wu * 8);
    }
    __syncthreads();
#pragma unroll
    for (int kk = 0; kk < 64; kk += 32) {
      bf16x8 af[4], bfr[4];
#pragma unroll
      for (int mt = 0; mt < 4; mt++)
        af[mt] = *(const bf16x8*)&a_lds[wm * 64 + mt * 16 + l15][kk + q * 8];
#pragma unroll
      for (int nt = 0; nt < 4; nt++)
        bfr[nt] = *(const bf16x8*)&b_lds[wn * 64 + nt * 16 + l15][kk + q * 8];
#pragma unroll
      for (int mt = 0; mt < 4; mt++)
#pragma unroll
        for (int nt = 0; nt < 4; nt++) acc[mt][nt] = MFMA16(af[mt], bfr[nt], acc[mt][nt]);
    }
    __syncthreads();
  }

  float be[4];
#pragma unroll
  for (int nt = 0; nt < 4; nt++)
    be[nt] = bf2f(b_enc[bn * 128 + wn * 64 + nt * 16 + l15]);
#pragma unroll
  for (int mt = 0; mt < 4; mt++)
#pragma unroll
    for (int nt = 0; nt < 4; nt++)
#pragma unroll
      for (int r = 0; r < 4; r++) {
        float v = tanh_(acc[mt][nt][r] + be[nt]);
        st_lds[wm * 64 + mt * 16 + q * 4 + r][wn * 64 + nt * 16 + l15] = f2bf(v);
      }
  __syncthreads();
#pragma unroll
  for (int p = 0; p < 8; p++) {
    int u_ = tid + p * 256;
    int r = u_ >> 4, w = u_ & 15;
    *(i32x4*)(states + (size_t)(bm * 128 + r) * H_ + bn * 128 + w * 8) =
        *(const i32x4*)&st_lds[r][w * 8];
  }
}

// ---------------------------------------------------------------- emit GEMM
// emit = states @ w_out^T + b_out: M=32768, K=512, N=50 (padded 64), fp32 out
__global__ __launch_bounds__(256) void emit_kernel(
    const unsigned short* __restrict__ states, const unsigned short* __restrict__ w_out,
    const unsigned short* __restrict__ b_out, float* __restrict__ emit) {
  const int tid = threadIdx.x;
  const int bm = blockIdx.x;
  const int wv = tid >> 6, lane = tid & 63, q = lane >> 4, l15 = lane & 15;
  const int wm = wv >> 1, wn = wv & 1;

  __shared__ __align__(16) unsigned short wo_lds[64][520];
  __shared__ __align__(16) unsigned short a_lds[128][72];

#pragma unroll
  for (int p = 0; p < 16; p++) {
    int u = tid + p * 256;
    int r = u >> 6, wu = u & 63;
    i32x4 v = {0, 0, 0, 0};
    if (r < KT) v = *(const i32x4*)(w_out + (size_t)r * H_ + wu * 8);
    *(i32x4*)&wo_lds[r][wu * 8] = v;
  }

  f32x4 acc[4][2];
#pragma unroll
  for (int mt = 0; mt < 4; mt++)
#pragma unroll
    for (int nt = 0; nt < 2; nt++) acc[mt][nt] = (f32x4){0.f, 0.f, 0.f, 0.f};

  for (int c = 0; c < 8; c++) {
    __syncthreads();
#pragma unroll
    for (int p = 0; p < 4; p++) {
      int u = tid + p * 256;
      int r = u >> 3, wu = u & 7;
      *(i32x4*)&a_lds[r][wu * 8] =
          *(const i32x4*)(states + (size_t)(bm * 128 + r) * H_ + c * 64 + wu * 8);
    }
    __syncthreads();
#pragma unroll
    for (int kk = 0; kk < 64; kk += 32) {
      bf16x8 af[4], bfr[2];
#pragma unroll
      for (int mt = 0; mt < 4; mt++)
        af[mt] = *(const bf16x8*)&a_lds[wm * 64 + mt * 16 + l15][kk + q * 8];
#pragma unroll
      for (int nt = 0; nt < 2; nt++)
        bfr[nt] = *(const bf16x8*)&wo_lds[wn * 32 + nt * 16 + l15][c * 64 + kk + q * 8];
#pragma unroll
      for (int mt = 0; mt < 4; mt++)
#pragma unroll
        for (int nt = 0; nt < 2; nt++) acc[mt][nt] = MFMA16(af[mt], bfr[nt], acc[mt][nt]);
    }
  }

  float bo[2];
#pragma unroll
  for (int nt = 0; nt < 2; nt++) {
    int n = wn * 32 + nt * 16 + l15;
    bo[nt] = (n < KT) ? bf2f(b_out[n]) : 0.f;
  }
#pragma unroll
  for (int mt = 0; mt < 4; mt++)
#pragma unroll
    for (int nt = 0; nt < 2; nt++) {
      int n = wn * 32 + nt * 16 + l15;
      if (n < KT) {
#pragma unroll
        for (int r = 0; r < 4; r++) {
          int m = bm * 128 + wm * 64 + mt * 16 + q * 4 + r;
          emit[(size_t)m * KT + n] = acc[mt][nt][r] + bo[nt];
        }
      }
    }
}

// ---------------------------------------------------------------- CRF forward
__global__ __launch_bounds__(256) void crf_kernel(
    const float* __restrict__ emit, const unsigned short* __restrict__ trans,
    const unsigned int* __restrict__ flag, void* __restrict__ out) {
  const int tid = threadIdx.x;
  const int wv = tid >> 6, lane = tid & 63;
  const int b = blockIdx.x * 4 + wv;
  const int jj = (lane < KT) ? lane : (KT - 1);

  float tr[KT];
  float mj = -1e30f;
#pragma unroll
  for (int i = 0; i < KT; i++) {
    tr[i] = bf2f(trans[jj * KT + i]);
    mj = fmaxf(mj, tr[i]);
  }
  float et[KT];
#pragma unroll
  for (int i = 0; i < KT; i++) et[i] = __expf(tr[i] - mj);
  float tr_stop = bf2f(trans[(KT - 1) * KT + jj]);

  float alpha = (lane == 0) ? 0.f : -1e30f;
  float e_next = emit[(size_t)b * KT + jj];

  for (int t = 0; t < T_; t++) {
    float e_cur = e_next;
    if (t < T_ - 1) e_next = emit[((size_t)(t + 1) * B_ + b) * KT + jj];
    float M = alpha;
#pragma unroll
    for (int off = 32; off; off >>= 1) M = fmaxf(M, __shfl_xor(M, off, 64));
    float p = __expf(alpha - M);
    float s = 0.f;
#pragma unroll
    for (int i = 0; i < KT; i++) {
      float pi = __uint_as_float(__builtin_amdgcn_readlane(__float_as_uint(p), i));
      s = __builtin_fmaf(et[i], pi, s);
    }
    float an = e_cur + mj + M + __logf(s);
    alpha = (lane < KT) ? an : -1e30f;
  }

  float v = (lane < KT) ? (alpha + tr_stop) : -1e30f;
  float M2 = v;
#pragma unroll
  for (int off = 32; off; off >>= 1) M2 = fmaxf(M2, __shfl_xor(M2, off, 64));
  float s2 = (lane < KT) ? __expf(v - M2) : 0.f;
#pragma unroll
  for (int off = 32; off; off >>= 1) s2 += __shfl_xor(s2, off, 64);
  float lz = M2 + __logf(s2);
  if (lane == 0) {
    if (*flag) ((unsigned short*)out)[b] = f2bf(lz);
    else ((float*)out)[b] = lz;
  }
}

// ---------------------------------------------------------------- launch
extern "C" void kernel_launch(void* const* d_in, const int* in_sizes, int n_in,
                              void* d_out, int out_size, void* d_ws, size_t ws_size,
                              hipStream_t stream) {
  const int* tokens = (const int*)d_in[0];
  const void* embed = d_in[1];
  const void* wih_f = d_in[2];
  const void* whh_f = d_in[3];
  const void* b_f = d_in[4];
  const void* wih_b = d_in[5];
  const void* whh_b = d_in[6];
  const void* b_b = d_in[7];
  const void* w_enc = d_in[8];
  const void* b_enc = d_in[9];
  const void* w_out = d_in[10];
  const void* b_out = d_in[11];
  const void* trans = d_in[12];

  char* ws = (char*)d_ws;
  // tags: [dir][wg] monotonic words, 16-dword (64B) stride = 4 KB total
  unsigned int* tags = (unsigned int*)ws;
  unsigned int* pflag = (unsigned int*)(ws + 262144);            // 256 B
  unsigned short* xbuf = (unsigned short*)(ws + 262400);         // 16 MB
  unsigned short* hf = (unsigned short*)(ws + 17039616);         // 32 MB
  unsigned short* hb = (unsigned short*)(ws + 50594048);         // 32 MB
  unsigned short* states = (unsigned short*)(ws + 84148480);     // 32 MB
  float* emit = (float*)(ws + 117702912);                        // 6.55 MB
  unsigned short* canon = (unsigned short*)(ws + 124256512);     // 7.4 MB

  unsigned short* c_wih_f = canon + 0;
  unsigned short* c_whh_f = canon + 524288;
  unsigned short* c_b_f   = canon + 1572864;
  unsigned short* c_wih_b = canon + 1574912;
  unsigned short* c_whh_b = canon + 2099200;
  unsigned short* c_b_b   = canon + 3147776;
  unsigned short* c_w_enc = canon + 3149824;
  unsigned short* c_b_enc = canon + 3674112;
  unsigned short* c_w_out = canon + 3674624;
  unsigned short* c_b_out = canon + 3700224;
  unsigned short* c_trans = canon + 3700352;

  hipMemsetAsync(tags, 0, 4096, stream);
  probe_kernel<<<1, 64, 0, stream>>>((const unsigned short*)embed, pflag);

  CvtPack pk;
  pk.a[0]  = {wih_f, c_wih_f, 524288};
  pk.a[1]  = {whh_f, c_whh_f, 1048576};
  pk.a[2]  = {b_f,   c_b_f,   2048};
  pk.a[3]  = {wih_b, c_wih_b, 524288};
  pk.a[4]  = {whh_b, c_whh_b, 1048576};
  pk.a[5]  = {b_b,   c_b_b,   2048};
  pk.a[6]  = {w_enc, c_w_enc, 524288};
  pk.a[7]  = {b_enc, c_b_enc, 512};
  pk.a[8]  = {w_out, c_w_out, 25600};
  pk.a[9]  = {b_out, c_b_out, 50};
  pk.a[10] = {trans, c_trans, 2500};
  convert_kernel<<<dim3(512, 11), 256, 0, stream>>>(pk, pflag);

  embed_kernel<<<(T_ * B_) / 8, 256, 0, stream>>>(tokens, embed, pflag, xbuf);
  lstm_kernel<<<64, 256, 0, stream>>>(c_whh_f, c_wih_f, c_b_f,
                                      c_whh_b, c_wih_b, c_b_b,
                                      xbuf, hf, hb, tags);
  enc_kernel<<<dim3(256, 4), 256, 0, stream>>>(hf, hb, c_w_enc, c_b_enc, states);
  emit_kernel<<<256, 256, 0, stream>>>(states, c_w_out, c_b_out, emit);
  crf_kernel<<<16, 256, 0, stream>>>(emit, c_trans, pflag, d_out);
}

// Round 5
// 2626.249 us; speedup vs baseline: 1.8524x; 1.1013x over previous
//
#include <hip/hip_runtime.h>
#include <stdint.h>

#define T_ 512
#define B_ 64
#define E_ 256
#define H_ 512
#define KT 50

typedef __attribute__((ext_vector_type(8))) short bf16x8;
typedef __attribute__((ext_vector_type(4))) float f32x4;
typedef __attribute__((ext_vector_type(4))) int i32x4;

#define MFMA16(a,b,c) __builtin_amdgcn_mfma_f32_16x16x32_bf16((a),(b),(c),0,0,0)

static __device__ __forceinline__ float bf2f(unsigned short v) {
  unsigned int u = ((unsigned int)v) << 16; float f; __builtin_memcpy(&f, &u, 4); return f;
}
static __device__ __forceinline__ unsigned short f2bf(float f) {
  unsigned int u; __builtin_memcpy(&u, &f, 4);
  u += 0x7fffu + ((u >> 16) & 1u);
  return (unsigned short)(u >> 16);
}
static __device__ __forceinline__ float sigm(float x) { return 1.f / (1.f + __expf(-x)); }
static __device__ __forceinline__ float tanh_(float x) { return 2.f / (1.f + __expf(-2.f * x)) - 1.f; }

// device-scope (MALL) dword load, self-waiting — for single-word tag polls
static __device__ __forceinline__ unsigned int load_dw_dev(const unsigned int* p) {
  unsigned int v;
  asm volatile("global_load_dword %0, %1, off sc0 sc1\n\ts_waitcnt vmcnt(0)"
               : "=v"(v) : "v"(p) : "memory");
  return v;
}

// ------------------------------------------------------------- dtype probe
__global__ void probe_kernel(const unsigned short* __restrict__ e,
                             unsigned int* __restrict__ flag) {
  int lane = threadIdx.x & 63;
  float a = fabsf(bf2f(e[2 * lane]));
  int good = (a >= 1e-8f && a <= 4.0f);
  unsigned long long m = __ballot(good);
  if (threadIdx.x == 0) flag[0] = (__popcll(m) >= 48) ? 1u : 0u;
}

// ------------------------------------------------------------- canonicalize
struct CvtArgs { const void* src; unsigned short* dst; int n; };
struct CvtPack { CvtArgs a[11]; };

__global__ __launch_bounds__(256) void convert_kernel(CvtPack p,
                                                      const unsigned int* __restrict__ flag) {
  CvtArgs c = p.a[blockIdx.y];
  int i = (blockIdx.x * 256 + threadIdx.x) * 8;
  if (i >= c.n) return;
  int isbf = *flag;
  if (i + 8 <= c.n) {
    if (isbf) {
      *(i32x4*)(c.dst + i) = *(const i32x4*)((const unsigned short*)c.src + i);
    } else {
      const float* s = (const float*)c.src;
      float4 a0 = *(const float4*)(s + i);
      float4 a1 = *(const float4*)(s + i + 4);
      unsigned short o[8] = {f2bf(a0.x), f2bf(a0.y), f2bf(a0.z), f2bf(a0.w),
                             f2bf(a1.x), f2bf(a1.y), f2bf(a1.z), f2bf(a1.w)};
      *(i32x4*)(c.dst + i) = *(i32x4*)o;
    }
  } else {
    for (int j = 0; j < 8; j++) {
      if (i + j < c.n) {
        c.dst[i + j] = isbf ? ((const unsigned short*)c.src)[i + j]
                            : f2bf(((const float*)c.src)[i + j]);
      }
    }
  }
}

// ---------------------------------------------------------------- embedding
__global__ __launch_bounds__(256) void embed_kernel(
    const int* __restrict__ tokens, const void* __restrict__ embed,
    const unsigned int* __restrict__ flag, unsigned short* __restrict__ x) {
  int tid = threadIdx.x;
  int row = blockIdx.x * 8 + (tid >> 5);   // row = t*64+b, 32768 rows
  int l = tid & 31;
  int tok = tokens[row];
  if (*flag) {
    const unsigned short* e = (const unsigned short*)embed;
    *(i32x4*)(x + (size_t)row * E_ + l * 8) =
        *(const i32x4*)(e + (size_t)tok * E_ + l * 8);
  } else {
    const float* e = (const float*)embed + (size_t)tok * E_ + l * 8;
    float4 a0 = *(const float4*)e;
    float4 a1 = *(const float4*)(e + 4);
    unsigned short o[8] = {f2bf(a0.x), f2bf(a0.y), f2bf(a0.z), f2bf(a0.w),
                           f2bf(a1.x), f2bf(a1.y), f2bf(a1.z), f2bf(a1.w)};
    *(i32x4*)(x + (size_t)row * E_ + l * 8) = *(i32x4*)o;
  }
}

// x-staging: 8 dwordx4 loads for one timestep, issued a step early so the
// HBM/L2 latency hides under gate math + publish + next step's tag wait.
// Exactness verified rounds 2-4.
#define ISSUE_BX(tt)                                                          \
  do {                                                                        \
    const unsigned short* xb_ = x + (size_t)(tt) * (B_ * E_);                 \
    const unsigned short* x0_ = xb_ + (size_t)(0 * 16 + l15) * E_ + (wv * 2 + 0) * 32 + q * 8; \
    const unsigned short* x1_ = xb_ + (size_t)(1 * 16 + l15) * E_ + (wv * 2 + 0) * 32 + q * 8; \
    const unsigned short* x2_ = xb_ + (size_t)(2 * 16 + l15) * E_ + (wv * 2 + 0) * 32 + q * 8; \
    const unsigned short* x3_ = xb_ + (size_t)(3 * 16 + l15) * E_ + (wv * 2 + 0) * 32 + q * 8; \
    const unsigned short* x4_ = xb_ + (size_t)(0 * 16 + l15) * E_ + (wv * 2 + 1) * 32 + q * 8; \
    const unsigned short* x5_ = xb_ + (size_t)(1 * 16 + l15) * E_ + (wv * 2 + 1) * 32 + q * 8; \
    const unsigned short* x6_ = xb_ + (size_t)(2 * 16 + l15) * E_ + (wv * 2 + 1) * 32 + q * 8; \
    const unsigned short* x7_ = xb_ + (size_t)(3 * 16 + l15) * E_ + (wv * 2 + 1) * 32 + q * 8; \
    asm volatile(                                                             \
        "global_load_dwordx4 %0, %8, off\n\t"                                 \
        "global_load_dwordx4 %1, %9, off\n\t"                                 \
        "global_load_dwordx4 %2, %10, off\n\t"                                \
        "global_load_dwordx4 %3, %11, off\n\t"                                \
        "global_load_dwordx4 %4, %12, off\n\t"                                \
        "global_load_dwordx4 %5, %13, off\n\t"                                \
        "global_load_dwordx4 %6, %14, off\n\t"                                \
        "global_load_dwordx4 %7, %15, off"                                    \
        : "=&v"(bxw[0]), "=&v"(bxw[1]), "=&v"(bxw[2]), "=&v"(bxw[3]),         \
          "=&v"(bxw[4]), "=&v"(bxw[5]), "=&v"(bxw[6]), "=&v"(bxw[7])          \
        : "v"(x0_), "v"(x1_), "v"(x2_), "v"(x3_),                             \
          "v"(x4_), "v"(x5_), "v"(x6_), "v"(x7_)                              \
        : "memory");                                                          \
  } while (0)

// ---------------------------------------------------------------- BiLSTM
// 64 blocks: dir = bid&1, wg = bid>>1. Weights pinned in VGPRs. Publish and
// gather ADDRESSES byte-identical to the harness-verified round-0 kernel.
// Transport = round-0 semantics (verified): publish 2 stores + vmcnt(0)
// drain, THEN monotonic tag store -> tag visible implies data visible.
//
// Round-5 schedule (r0 order restored; r4 A/B showed moving x-MFMAs after
// the gate regresses — they must OVERLAP the producers' drain+tag window):
//   [x-wait counted][x-MFMAs][per-wave tag gate][issue 16 gathers]
//   [vmcnt(12) h-MFMA kl0][vmcnt(8) kl1][vmcnt(4) kl2][vmcnt(0) kl3]
//   [sync][pacc][sync][ISSUE_BX next][gate math][sync][wv0 publish+drain+tag]
//  - per-wave tag gate (r4, verified): wave wv needs only producers
//    wv*8..wv*8+9; 64-lane poll of <=10 cold tag words, s_sleep backoff.
//  - chunked gather consume: after the gate's internal vmcnt(0), every wave
//    has exactly 16 outstanding loads -> uniform counted waits overlap
//    h-MFMA issue with remaining load returns.
__global__ __launch_bounds__(256, 1) void lstm_kernel(
    const unsigned short* __restrict__ whh_f, const unsigned short* __restrict__ wih_f,
    const unsigned short* __restrict__ bias_f,
    const unsigned short* __restrict__ whh_b, const unsigned short* __restrict__ wih_b,
    const unsigned short* __restrict__ bias_b,
    const unsigned short* __restrict__ x,
    unsigned short* __restrict__ hf, unsigned short* __restrict__ hb,
    unsigned int* __restrict__ tags) {
  const int tid = threadIdx.x;
  const int wv = tid >> 6, lane = tid & 63, q = lane >> 4, l15 = lane & 15;
  const int bid = blockIdx.x;
  const int dir = bid & 1;
  const int wg = bid >> 1;            // 0..31 within direction
  const int u0 = wg * 16;

  const unsigned short* whh = dir ? whh_b : whh_f;
  const unsigned short* wih = dir ? wih_b : wih_f;
  const unsigned short* bvec = dir ? bias_b : bias_f;
  unsigned short* hbuf = dir ? hb : hf;
  unsigned int* tbase = tags + (size_t)dir * 512;  // 32 tags, 16-dword stride

  // ---- preload weight A-fragments: afrag[gate mt][k-chunk kl]
  bf16x8 afrag[4][6];
#pragma unroll
  for (int mt = 0; mt < 4; mt++) {
    int row = mt * H_ + u0 + l15;
#pragma unroll
    for (int kl = 0; kl < 6; kl++) {
      const unsigned short* p = (kl < 4)
          ? (whh + (size_t)row * H_ + (wv * 4 + kl) * 32 + q * 8)
          : (wih + (size_t)row * E_ + (wv * 2 + (kl - 4)) * 32 + q * 8);
      afrag[mt][kl] = *(const bf16x8*)p;
    }
  }

  // per-wave producer-tag pointer: producers wv*8 .. wv*8+9 (clamped to 31)
  int poff = (l15 < 10) ? l15 : 0;
  int pidx = wv * 8 + poff;
  if (pidx > 31) pidx = 31;
  const unsigned int* my_tp = tbase + (size_t)pidx * 16;

  const int eb = tid & 63;
  const int uu = tid >> 6;
  float bg[4][4];
#pragma unroll
  for (int s = 0; s < 4; s++) {
    int u = uu + 4 * s;
#pragma unroll
    for (int g = 0; g < 4; g++) bg[s][g] = bf2f(bvec[g * H_ + u0 + u]);
  }
  float cst[4] = {0.f, 0.f, 0.f, 0.f};

  __shared__ float pacc[4][64][66];
  __shared__ __align__(16) unsigned short h_out[64][16];

  i32x4 bxw[8];
  // prologue: stage x for step 0
  ISSUE_BX(dir ? (T_ - 1) : 0);

  for (int step = 0; step < T_; step++) {
    const int t = dir ? (T_ - 1 - step) : step;
    f32x4 acc[4][4];
#pragma unroll
    for (int mt = 0; mt < 4; mt++)
#pragma unroll
      for (int nt = 0; nt < 4; nt++) acc[mt][nt] = (f32x4){0.f, 0.f, 0.f, 0.f};

    // ---- x-wait (counted): wv0 has only its tag store outstanding (its bx
    // loads were drained by the publish vmcnt(0)); others have 8 bx loads.
    if (step == 0) {
      asm volatile("s_waitcnt vmcnt(0)" ::: "memory");
    } else if (wv == 0) {
      asm volatile("s_waitcnt vmcnt(1)" ::: "memory");  // tag store residue
    } else {
      asm volatile("s_waitcnt vmcnt(0)" ::: "memory");
    }
    __builtin_amdgcn_sched_barrier(0);

    // ---- x-part MFMAs FIRST (overlap other blocks' publish drain + tag RT)
#pragma unroll
    for (int kl = 0; kl < 2; kl++) {
#pragma unroll
      for (int nt = 0; nt < 4; nt++) {
        bf16x8 b_;
        __builtin_memcpy(&b_, &bxw[kl * 4 + nt], 16);
#pragma unroll
        for (int mt = 0; mt < 4; mt++)
          acc[mt][nt] = MFMA16(afrag[mt][4 + kl], b_, acc[mt][nt]);
      }
    }

    if (step > 0) {
      __builtin_amdgcn_sched_barrier(0);  // keep x-MFMAs above the gate

      // ---- per-wave tag gate (cold region, <=10 unique dwords, backoff)
      for (;;) {
        unsigned int v = load_dw_dev(my_tp);
        if (__ballot(v >= (unsigned)step) == ~0ULL) break;
        __builtin_amdgcn_s_sleep(1);
      }
      asm volatile("" ::: "memory");  // no hoisting of gather above the gate

      // ---- gather: issue 16 device-scope loads (outstanding now exactly 16
      // for every wave; the gate's internal vmcnt(0) drained everything else)
      const int tprev = dir ? (t + 1) : (t - 1);
      const unsigned int* hD = (const unsigned int*)hbuf + (size_t)tprev * 16384;
      const unsigned int* a0 = hD + ((wv * 4 + 0) * 4 + q) * 256 + l15 * 4;
      const unsigned int* a1 = hD + ((wv * 4 + 1) * 4 + q) * 256 + l15 * 4;
      const unsigned int* a2 = hD + ((wv * 4 + 2) * 4 + q) * 256 + l15 * 4;
      const unsigned int* a3 = hD + ((wv * 4 + 3) * 4 + q) * 256 + l15 * 4;
      i32x4 hr4[16];
      asm volatile(
          "global_load_dwordx4 %0, %16, off sc0 sc1\n\t"
          "global_load_dwordx4 %1, %16, off offset:1024 sc0 sc1\n\t"
          "global_load_dwordx4 %2, %16, off offset:2048 sc0 sc1\n\t"
          "global_load_dwordx4 %3, %16, off offset:3072 sc0 sc1\n\t"
          "global_load_dwordx4 %4, %17, off sc0 sc1\n\t"
          "global_load_dwordx4 %5, %17, off offset:1024 sc0 sc1\n\t"
          "global_load_dwordx4 %6, %17, off offset:2048 sc0 sc1\n\t"
          "global_load_dwordx4 %7, %17, off offset:3072 sc0 sc1\n\t"
          "global_load_dwordx4 %8, %18, off sc0 sc1\n\t"
          "global_load_dwordx4 %9, %18, off offset:1024 sc0 sc1\n\t"
          "global_load_dwordx4 %10, %18, off offset:2048 sc0 sc1\n\t"
          "global_load_dwordx4 %11, %18, off offset:3072 sc0 sc1\n\t"
          "global_load_dwordx4 %12, %19, off sc0 sc1\n\t"
          "global_load_dwordx4 %13, %19, off offset:1024 sc0 sc1\n\t"
          "global_load_dwordx4 %14, %19, off offset:2048 sc0 sc1\n\t"
          "global_load_dwordx4 %15, %19, off offset:3072 sc0 sc1"
          : "=&v"(hr4[0]), "=&v"(hr4[1]), "=&v"(hr4[2]), "=&v"(hr4[3]),
            "=&v"(hr4[4]), "=&v"(hr4[5]), "=&v"(hr4[6]), "=&v"(hr4[7]),
            "=&v"(hr4[8]), "=&v"(hr4[9]), "=&v"(hr4[10]), "=&v"(hr4[11]),
            "=&v"(hr4[12]), "=&v"(hr4[13]), "=&v"(hr4[14]), "=&v"(hr4[15])
          : "v"(a0), "v"(a1), "v"(a2), "v"(a3)
          : "memory");

      // ---- chunked consume: quad j = hr4[j*4..j*4+3] (kl=j, nt=0..3);
      // loads retire in issue order -> vmcnt(12/8/4/0) gates quads 0..3.
#pragma unroll
      for (int kl = 0; kl < 4; kl++) {
        if (kl == 0)      asm volatile("s_waitcnt vmcnt(12)" ::: "memory");
        else if (kl == 1) asm volatile("s_waitcnt vmcnt(8)" ::: "memory");
        else if (kl == 2) asm volatile("s_waitcnt vmcnt(4)" ::: "memory");
        else              asm volatile("s_waitcnt vmcnt(0)" ::: "memory");
        __builtin_amdgcn_sched_barrier(0);
#pragma unroll
        for (int nt = 0; nt < 4; nt++) {
          bf16x8 bh;
          __builtin_memcpy(&bh, &hr4[kl * 4 + nt], 16);
#pragma unroll
          for (int mt = 0; mt < 4; mt++)
            acc[mt][nt] = MFMA16(afrag[mt][kl], bh, acc[mt][nt]);
        }
      }
    }

    __syncthreads();
#pragma unroll
    for (int mt = 0; mt < 4; mt++)
#pragma unroll
      for (int nt = 0; nt < 4; nt++)
#pragma unroll
        for (int r = 0; r < 4; r++)
          pacc[wv][mt * 16 + q * 4 + r][nt * 16 + l15] = acc[mt][nt][r];
    __syncthreads();

    // stage x for the NEXT step now — latency hides under gate math +
    // publish + next step's tag wait
    if (step < T_ - 1) ISSUE_BX(dir ? (T_ - 2 - step) : (step + 1));

#pragma unroll
    for (int s = 0; s < 4; s++) {
      int u = uu + 4 * s;
      float gi = bg[s][0], gf = bg[s][1], gg = bg[s][2], og = bg[s][3];
#pragma unroll
      for (int w = 0; w < 4; w++) {
        gi += pacc[w][u][eb];
        gf += pacc[w][16 + u][eb];
        gg += pacc[w][32 + u][eb];
        og += pacc[w][48 + u][eb];
      }
      float cn = sigm(gf) * cst[s] + sigm(gi) * tanh_(gg);
      cst[s] = cn;
      h_out[eb][u] = f2bf(sigm(og) * tanh_(cn));
    }
    __syncthreads();

    if (wv == 0) {  // publish: 2 vec stores + one drain, then tag (monotonic)
      unsigned int* gp = (unsigned int*)hbuf + (size_t)t * 16384 + wg * 512 + lane * 4;
      i32x4 v0 = *(const i32x4*)&h_out[lane][0];
      i32x4 v1 = *(const i32x4*)&h_out[lane][8];
      asm volatile(
          "global_store_dwordx4 %0, %1, off sc0 sc1\n\t"
          "global_store_dwordx4 %0, %2, off offset:1024 sc0 sc1\n\t"
          "s_waitcnt vmcnt(0)"
          :: "v"(gp), "v"(v0), "v"(v1) : "memory");
      if (lane == 0) {
        unsigned int* tp = tbase + (size_t)wg * 16;
        unsigned int tv = (unsigned int)(step + 1);
        asm volatile("global_store_dword %0, %1, off sc0 sc1"
                     :: "v"(tp), "v"(tv) : "memory");
      }
    }
  }
}

// ---------------------------------------------------------------- encoder GEMM
// states = tanh([hf|hb] @ w_enc^T + b_enc): M=32768, K=1024, N=512.
__global__ __launch_bounds__(256) void enc_kernel(
    const unsigned short* __restrict__ hf, const unsigned short* __restrict__ hb,
    const unsigned short* __restrict__ w_enc, const unsigned short* __restrict__ b_enc,
    unsigned short* __restrict__ states) {
  const int tid = threadIdx.x;
  const int bm = blockIdx.x, bn = blockIdx.y;
  const int wv = tid >> 6, lane = tid & 63, q = lane >> 4, l15 = lane & 15;
  const int wm = wv >> 1, wn = wv & 1;

  __shared__ __align__(16) unsigned short a_lds[128][72];
  __shared__ __align__(16) unsigned short b_lds[128][72];
  __shared__ __align__(16) unsigned short st_lds[128][136];

  f32x4 acc[4][4];
#pragma unroll
  for (int mt = 0; mt < 4; mt++)
#pragma unroll
    for (int nt = 0; nt < 4; nt++) acc[mt][nt] = (f32x4){0.f, 0.f, 0.f, 0.f};

  for (int c = 0; c < 16; c++) {
    const unsigned short* asrc = (c < 8) ? hf : hb;
    int kof = (c & 7) * 64;
#pragma unroll
    for (int p = 0; p < 4; p++) {
      int u_ = tid + p * 256;
      int r = u_ >> 3, wu = u_ & 7;
      int grow = bm * 128 + r;   // t = grow>>6, b = grow&63
      *(i32x4*)&a_lds[r][wu * 8] =
          *(const i32x4*)((const unsigned int*)asrc + (size_t)(grow >> 6) * 16384 +
                          (size_t)((kof >> 3) + wu) * 256 + (grow & 63) * 4);
      *(i32x4*)&b_lds[r][wu * 8] =
          *(const i32x4*)(w_enc + (size_t)(bn * 128 + r) * 1024 + c * 64 + wu * 8);
    }
    __syncthreads();
#pragma unroll
    for (int kk = 0; kk < 64; kk += 32) {
      bf16x8 af[4], bfr[4];
#pragma unroll
      for (int mt = 0; mt < 4; mt++)
        af[mt] = *(const bf16x8*)&a_lds[wm * 64 + mt * 16 + l15][kk + q * 8];
#pragma unroll
      for (int nt = 0; nt < 4; nt++)
        bfr[nt] = *(const bf16x8*)&b_lds[wn * 64 + nt * 16 + l15][kk + q * 8];
#pragma unroll
      for (int mt = 0; mt < 4; mt++)
#pragma unroll
        for (int nt = 0; nt < 4; nt++) acc[mt][nt] = MFMA16(af[mt], bfr[nt], acc[mt][nt]);
    }
    __syncthreads();
  }

  float be[4];
#pragma unroll
  for (int nt = 0; nt < 4; nt++)
    be[nt] = bf2f(b_enc[bn * 128 + wn * 64 + nt * 16 + l15]);
#pragma unroll
  for (int mt = 0; mt < 4; mt++)
#pragma unroll
    for (int nt = 0; nt < 4; nt++)
#pragma unroll
      for (int r = 0; r < 4; r++) {
        float v = tanh_(acc[mt][nt][r] + be[nt]);
        st_lds[wm * 64 + mt * 16 + q * 4 + r][wn * 64 + nt * 16 + l15] = f2bf(v);
      }
  __syncthreads();
#pragma unroll
  for (int p = 0; p < 8; p++) {
    int u_ = tid + p * 256;
    int r = u_ >> 4, w = u_ & 15;
    *(i32x4*)(states + (size_t)(bm * 128 + r) * H_ + bn * 128 + w * 8) =
        *(const i32x4*)&st_lds[r][w * 8];
  }
}

// ---------------------------------------------------------------- emit GEMM
// emit = states @ w_out^T + b_out: M=32768, K=512, N=50 (padded 64), fp32 out
__global__ __launch_bounds__(256) void emit_kernel(
    const unsigned short* __restrict__ states, const unsigned short* __restrict__ w_out,
    const unsigned short* __restrict__ b_out, float* __restrict__ emit) {
  const int tid = threadIdx.x;
  const int bm = blockIdx.x;
  const int wv = tid >> 6, lane = tid & 63, q = lane >> 4, l15 = lane & 15;
  const int wm = wv >> 1, wn = wv & 1;

  __shared__ __align__(16) unsigned short wo_lds[64][520];
  __shared__ __align__(16) unsigned short a_lds[128][72];

#pragma unroll
  for (int p = 0; p < 16; p++) {
    int u = tid + p * 256;
    int r = u >> 6, wu = u & 63;
    i32x4 v = {0, 0, 0, 0};
    if (r < KT) v = *(const i32x4*)(w_out + (size_t)r * H_ + wu * 8);
    *(i32x4*)&wo_lds[r][wu * 8] = v;
  }

  f32x4 acc[4][2];
#pragma unroll
  for (int mt = 0; mt < 4; mt++)
#pragma unroll
    for (int nt = 0; nt < 2; nt++) acc[mt][nt] = (f32x4){0.f, 0.f, 0.f, 0.f};

  for (int c = 0; c < 8; c++) {
    __syncthreads();
#pragma unroll
    for (int p = 0; p < 4; p++) {
      int u = tid + p * 256;
      int r = u >> 3, wu = u & 7;
      *(i32x4*)&a_lds[r][wu * 8] =
          *(const i32x4*)(states + (size_t)(bm * 128 + r) * H_ + c * 64 + wu * 8);
    }
    __syncthreads();
#pragma unroll
    for (int kk = 0; kk < 64; kk += 32) {
      bf16x8 af[4], bfr[2];
#pragma unroll
      for (int mt = 0; mt < 4; mt++)
        af[mt] = *(const bf16x8*)&a_lds[wm * 64 + mt * 16 + l15][kk + q * 8];
#pragma unroll
      for (int nt = 0; nt < 2; nt++)
        bfr[nt] = *(const bf16x8*)&wo_lds[wn * 32 + nt * 16 + l15][c * 64 + kk + q * 8];
#pragma unroll
      for (int mt = 0; mt < 4; mt++)
#pragma unroll
        for (int nt = 0; nt < 2; nt++) acc[mt][nt] = MFMA16(af[mt], bfr[nt], acc[mt][nt]);
    }
  }

  float bo[2];
#pragma unroll
  for (int nt = 0; nt < 2; nt++) {
    int n = wn * 32 + nt * 16 + l15;
    bo[nt] = (n < KT) ? bf2f(b_out[n]) : 0.f;
  }
#pragma unroll
  for (int mt = 0; mt < 4; mt++)
#pragma unroll
    for (int nt = 0; nt < 2; nt++) {
      int n = wn * 32 + nt * 16 + l15;
      if (n < KT) {
#pragma unroll
        for (int r = 0; r < 4; r++) {
          int m = bm * 128 + wm * 64 + mt * 16 + q * 4 + r;
          emit[(size_t)m * KT + n] = acc[mt][nt][r] + bo[nt];
        }
      }
    }
}

// ---------------------------------------------------------------- CRF forward
__global__ __launch_bounds__(256) void crf_kernel(
    const float* __restrict__ emit, const unsigned short* __restrict__ trans,
    const unsigned int* __restrict__ flag, void* __restrict__ out) {
  const int tid = threadIdx.x;
  const int wv = tid >> 6, lane = tid & 63;
  const int b = blockIdx.x * 4 + wv;
  const int jj = (lane < KT) ? lane : (KT - 1);

  float tr[KT];
  float mj = -1e30f;
#pragma unroll
  for (int i = 0; i < KT; i++) {
    tr[i] = bf2f(trans[jj * KT + i]);
    mj = fmaxf(mj, tr[i]);
  }
  float et[KT];
#pragma unroll
  for (int i = 0; i < KT; i++) et[i] = __expf(tr[i] - mj);
  float tr_stop = bf2f(trans[(KT - 1) * KT + jj]);

  float alpha = (lane == 0) ? 0.f : -1e30f;
  float e_next = emit[(size_t)b * KT + jj];

  for (int t = 0; t < T_; t++) {
    float e_cur = e_next;
    if (t < T_ - 1) e_next = emit[((size_t)(t + 1) * B_ + b) * KT + jj];
    float M = alpha;
#pragma unroll
    for (int off = 32; off; off >>= 1) M = fmaxf(M, __shfl_xor(M, off, 64));
    float p = __expf(alpha - M);
    float s = 0.f;
#pragma unroll
    for (int i = 0; i < KT; i++) {
      float pi = __uint_as_float(__builtin_amdgcn_readlane(__float_as_uint(p), i));
      s = __builtin_fmaf(et[i], pi, s);
    }
    float an = e_cur + mj + M + __logf(s);
    alpha = (lane < KT) ? an : -1e30f;
  }

  float v = (lane < KT) ? (alpha + tr_stop) : -1e30f;
  float M2 = v;
#pragma unroll
  for (int off = 32; off; off >>= 1) M2 = fmaxf(M2, __shfl_xor(M2, off, 64));
  float s2 = (lane < KT) ? __expf(v - M2) : 0.f;
#pragma unroll
  for (int off = 32; off; off >>= 1) s2 += __shfl_xor(s2, off, 64);
  float lz = M2 + __logf(s2);
  if (lane == 0) {
    if (*flag) ((unsigned short*)out)[b] = f2bf(lz);
    else ((float*)out)[b] = lz;
  }
}

// ---------------------------------------------------------------- launch
extern "C" void kernel_launch(void* const* d_in, const int* in_sizes, int n_in,
                              void* d_out, int out_size, void* d_ws, size_t ws_size,
                              hipStream_t stream) {
  const int* tokens = (const int*)d_in[0];
  const void* embed = d_in[1];
  const void* wih_f = d_in[2];
  const void* whh_f = d_in[3];
  const void* b_f = d_in[4];
  const void* wih_b = d_in[5];
  const void* whh_b = d_in[6];
  const void* b_b = d_in[7];
  const void* w_enc = d_in[8];
  const void* b_enc = d_in[9];
  const void* w_out = d_in[10];
  const void* b_out = d_in[11];
  const void* trans = d_in[12];

  char* ws = (char*)d_ws;
  // tags: [dir][wg] monotonic words, 16-dword (64B) stride = 4 KB total
  unsigned int* tags = (unsigned int*)ws;
  unsigned int* pflag = (unsigned int*)(ws + 262144);            // 256 B
  unsigned short* xbuf = (unsigned short*)(ws + 262400);         // 16 MB
  unsigned short* hf = (unsigned short*)(ws + 17039616);         // 32 MB
  unsigned short* hb = (unsigned short*)(ws + 50594048);         // 32 MB
  unsigned short* states = (unsigned short*)(ws + 84148480);     // 32 MB
  float* emit = (float*)(ws + 117702912);                        // 6.55 MB
  unsigned short* canon = (unsigned short*)(ws + 124256512);     // 7.4 MB

  unsigned short* c_wih_f = canon + 0;
  unsigned short* c_whh_f = canon + 524288;
  unsigned short* c_b_f   = canon + 1572864;
  unsigned short* c_wih_b = canon + 1574912;
  unsigned short* c_whh_b = canon + 2099200;
  unsigned short* c_b_b   = canon + 3147776;
  unsigned short* c_w_enc = canon + 3149824;
  unsigned short* c_b_enc = canon + 3674112;
  unsigned short* c_w_out = canon + 3674624;
  unsigned short* c_b_out = canon + 3700224;
  unsigned short* c_trans = canon + 3700352;

  hipMemsetAsync(tags, 0, 4096, stream);
  probe_kernel<<<1, 64, 0, stream>>>((const unsigned short*)embed, pflag);

  CvtPack pk;
  pk.a[0]  = {wih_f, c_wih_f, 524288};
  pk.a[1]  = {whh_f, c_whh_f, 1048576};
  pk.a[2]  = {b_f,   c_b_f,   2048};
  pk.a[3]  = {wih_b, c_wih_b, 524288};
  pk.a[4]  = {whh_b, c_whh_b, 1048576};
  pk.a[5]  = {b_b,   c_b_b,   2048};
  pk.a[6]  = {w_enc, c_w_enc, 524288};
  pk.a[7]  = {b_enc, c_b_enc, 512};
  pk.a[8]  = {w_out, c_w_out, 25600};
  pk.a[9]  = {b_out, c_b_out, 50};
  pk.a[10] = {trans, c_trans, 2500};
  convert_kernel<<<dim3(512, 11), 256, 0, stream>>>(pk, pflag);

  embed_kernel<<<(T_ * B_) / 8, 256, 0, stream>>>(tokens, embed, pflag, xbuf);
  lstm_kernel<<<64, 256, 0, stream>>>(c_whh_f, c_wih_f, c_b_f,
                                      c_whh_b, c_wih_b, c_b_b,
                                      xbuf, hf, hb, tags);
  enc_kernel<<<dim3(256, 4), 256, 0, stream>>>(hf, hb, c_w_enc, c_b_enc, states);
  emit_kernel<<<256, 256, 0, stream>>>(states, c_w_out, c_b_out, emit);
  crf_kernel<<<16, 256, 0, stream>>>(emit, c_trans, pflag, d_out);
}